// Round 2
// baseline (303.368 us; speedup 1.0000x reference)
//
#include <hip/hip_runtime.h>
#include <cstdint>
#include <cstddef>

#define HIDDEN 1024
#define BATCH 4
#define SEQ 4096
#define M_ROWS (BATCH * SEQ)   // 16384
#define K_DIM 1024
#define SUBCHUNK 32
#define NSUB (SEQ / SUBCHUNK)  // 128

typedef __bf16 bf16_t;
typedef __bf16 v8bf __attribute__((ext_vector_type(8)));
typedef float v4f __attribute__((ext_vector_type(4)));

__device__ __forceinline__ unsigned short f32_to_bf16(float f) {
  unsigned int u = __float_as_uint(f);
  u += 0x7fffu + ((u >> 16) & 1u);   // round-to-nearest-even
  return (unsigned short)(u >> 16);
}
__device__ __forceinline__ float bf16_to_f32(unsigned short u) {
  return __uint_as_float((unsigned int)u << 16);
}

// ---- Merged convert: X fp32->bf16 (blocks 0..16383) and
//      Wb = (W0+W1)/8 | W1 | W2 as bf16 (blocks 16384..19455) ----
__global__ void convert_kernel(const float* __restrict__ X,
                               const float* __restrict__ W0,
                               const float* __restrict__ W1,
                               const float* __restrict__ W2,
                               unsigned short* __restrict__ Xb,
                               unsigned short* __restrict__ Wb) {
  int bx = blockIdx.x;
  if (bx < 16384) {
    int i = bx * 256 + threadIdx.x;        // over 4,194,304 float4s (exact)
    float4 f = ((const float4*)X)[i];
    ushort4 u;
    u.x = f32_to_bf16(f.x); u.y = f32_to_bf16(f.y);
    u.z = f32_to_bf16(f.z); u.w = f32_to_bf16(f.w);
    ((ushort4*)Xb)[i] = u;
  } else {
    int i = (bx - 16384) * 256 + threadIdx.x;  // over 786,432 float4s (exact)
    int mat = i >> 18;                          // 262,144 float4 per matrix
    int off = i & 0x3FFFF;
    float4 f;
    if (mat == 0) {
      float4 a = ((const float4*)W0)[off];
      float4 b = ((const float4*)W1)[off];
      f.x = (a.x + b.x) * 0.125f; f.y = (a.y + b.y) * 0.125f;
      f.z = (a.z + b.z) * 0.125f; f.w = (a.w + b.w) * 0.125f;
    } else {
      const float* src = (mat == 1) ? W1 : W2;
      f = ((const float4*)src)[off];
    }
    ushort4 u;
    u.x = f32_to_bf16(f.x); u.y = f32_to_bf16(f.y);
    u.z = f32_to_bf16(f.z); u.w = f32_to_bf16(f.w);
    ((ushort4*)Wb)[i] = u;
  }
}

// ---- Persistent bf16 GEMM, 256x256 tile, BK=64, 8 waves, 8-phase counted
// vmcnt schedule.  256 blocks (1/CU), 3 tiles each; tile r's K-loop tail
// stages tile r+1's first K-tiles into the freed LDS buffers (post-tail
// vmcnt state == post-prologue state), so the epilogue overlaps next-tile
// load latency and next-tile MFMA overlaps the store drain.
// C[m][n] = sum_k A[m][k]*B[n][k];  A:[16384][1024], B:[3072][1024] (B^T).
// mat==0 tiles run fused in-subchunk-cummax epilogue; mat 1/2 store C1/C2.
// LDS: 128 KiB dynamic = 2 dbuf x (A 256x64 + B 256x64) bf16.
__global__ __launch_bounds__(512, 2) void gemm256_kernel(
    const bf16_t* __restrict__ A, const bf16_t* __restrict__ B,
    unsigned short* __restrict__ Lp, unsigned short* __restrict__ C1p,
    unsigned short* __restrict__ C2p, float* __restrict__ cmax) {
  extern __shared__ __align__(16) char smem[];   // 131072 B

  const int tid = threadIdx.x;
  const int wave = tid >> 6;     // 0..7
  const int lane = tid & 63;
  const int quad = lane >> 4;    // 0..3
  const int r16 = lane & 15;
  const int wr = wave >> 2;      // 0..1 -> 128-row half
  const int wc = wave & 3;       // 0..3 -> 64-col quarter

  // Staging: LDS dest is linear (base + lane*16); swizzle applied on the
  // GLOBAL source address. LDS slot (row m, 16B-chunk c) holds global
  // k-chunk c ^ (m&7).  Lane l covers row (+l>>3), chunk l&7 -> source
  // chunk (l&7)^(l>>3).
  const int l3 = lane >> 3;
  const int lc = lane & 7;
  const size_t laneOff = (size_t)l3 * K_DIM + (size_t)((lc ^ l3) << 3);

  // ds_read addressing: row m = wr*128 + i*16 + r16 (A) / wc*64 + j*16 + r16 (B),
  // desired chunk kk*4+quad stored at chunk (kk*4+quad)^(r16&7).
  const int aRow = (wr * 128 + r16) * 128;   // bytes (row stride 128B)
  const int bRow = (wc * 64 + r16) * 128;
  const int cxor = (r16 & 7) * 16;
  const int qx = quad * 16;

  v4f acc[8][4];
  v8bf afr[4];
  v8bf bfr[4][2];

#define STG_A(P, d, q, kt) __builtin_amdgcn_global_load_lds( \
    (__attribute__((address_space(1))) void*)((P) + (size_t)(q) * (64 * K_DIM) + (size_t)(kt) * 64), \
    (__attribute__((address_space(3))) void*)(smem + (d) * 32768 + (q) * 8192 + wave * 1024), 16, 0, 0)
#define STG_B(P, d, q, kt) __builtin_amdgcn_global_load_lds( \
    (__attribute__((address_space(1))) void*)((P) + (size_t)(q) * (64 * K_DIM) + (size_t)(kt) * 64), \
    (__attribute__((address_space(3))) void*)(smem + 65536 + (d) * 32768 + (q) * 8192 + wave * 1024), 16, 0, 0)
#define LDA(d, i, kk) (*(const v8bf*)(smem + (d) * 32768 + aRow + (i) * 2048 + (((kk) * 64 + qx) ^ cxor)))
#define LDB(d, j, kk) (*(const v8bf*)(smem + 65536 + (d) * 32768 + bRow + (j) * 2048 + (((kk) * 64 + qx) ^ cxor)))
#define RD_A(d, ih, kk) { _Pragma("unroll") for (int ii = 0; ii < 4; ++ii) afr[ii] = LDA(d, (ih) * 4 + ii, kk); }
#define RD_B(d, kk) { _Pragma("unroll") for (int j = 0; j < 4; ++j) bfr[j][kk] = LDB(d, j, kk); }
#define MM(ih, kk) \
  __builtin_amdgcn_s_barrier(); \
  asm volatile("s_waitcnt lgkmcnt(0)" ::: "memory"); \
  __builtin_amdgcn_s_setprio(1); \
  { _Pragma("unroll") for (int ii = 0; ii < 4; ++ii) { _Pragma("unroll") for (int j = 0; j < 4; ++j) \
      acc[(ih) * 4 + ii][j] = __builtin_amdgcn_mfma_f32_16x16x32_bf16(afr[ii], bfr[j][(kk)], acc[(ih) * 4 + ii][j], 0, 0, 0); } } \
  __builtin_amdgcn_s_setprio(0);
#define BAR() __builtin_amdgcn_s_barrier()
#define WAITV(n) asm volatile("s_waitcnt vmcnt(" #n ")" ::: "memory")

#pragma unroll 1
  for (int r = 0; r < 3; ++r) {
    // Bijective XCD swizzle over the 768 logical tiles: tile g = bid + 256r,
    // swz = (g&7)*96 + g/8; same XCD gets the same tile set as the R1 grid.
    const int orig = (int)blockIdx.x + (r << 8);
    const int swz = (orig & 7) * 96 + (orig >> 3);
    const int bx = swz % 12;       // n-tile (12 = 3 matrices x 4 tiles)
    const int mt = swz / 12;       // m-tile (64)
    const int mtile0 = mt * 256;
    const int nbase = bx * 256;
    const bf16_t* Ag = A + (size_t)(mtile0 + wave * 8) * K_DIM + laneOff;
    const bf16_t* Bg = B + (size_t)(nbase + wave * 8) * K_DIM + laneOff;
    // next tile's pointers (used only when r < 2)
    const int orig2 = (int)blockIdx.x + (((r < 2) ? r + 1 : 0) << 8);
    const int swz2 = (orig2 & 7) * 96 + (orig2 >> 3);
    const bf16_t* Ag2 = A + (size_t)((swz2 / 12) * 256 + wave * 8) * K_DIM + laneOff;
    const bf16_t* Bg2 = B + (size_t)((swz2 % 12) * 256 + wave * 8) * K_DIM + laneOff;

#pragma unroll
    for (int i = 0; i < 8; ++i)
#pragma unroll
      for (int j = 0; j < 4; ++j) acc[i][j] = (v4f)(0.0f);

    if (r == 0) {
      // Cold prologue: tile0 full -> buf0 (8 oldest), tile1 partial -> buf1 (4)
      STG_A(Ag, 0, 0, 0); STG_A(Ag, 0, 1, 0); STG_A(Ag, 0, 2, 0); STG_A(Ag, 0, 3, 0);
      STG_B(Bg, 0, 0, 0); STG_B(Bg, 0, 1, 0); STG_B(Bg, 0, 2, 0); STG_B(Bg, 0, 3, 0);
      STG_A(Ag, 1, 0, 1); STG_A(Ag, 1, 2, 1); STG_B(Bg, 1, 0, 1); STG_B(Bg, 1, 1, 1);
      WAITV(4);                    // drain tile0's 8; leave tile1's 4 in flight
      BAR();
    }
    // For r > 0: previous tail established the same state (buf0 ready,
    // 4 K-tile-1 loads in flight, barrier passed).

    // ---- Main loop: iter computes K-tiles 2it (buf0), 2it+1 (buf1);
    //      stages 2it+1 remainder, 2it+2 (buf0), 2it+3 (buf1 start). ----
    for (int it = 0; it < 7; ++it) {
      const int t1 = 2 * it + 1, t2 = t1 + 1, t3 = t1 + 2;
      // ph1: buf0 (ih0,kk0); B1.Q2/Q3 <- t1
      RD_A(0, 0, 0); RD_B(0, 0);
      STG_B(Bg, 1, 2, t1); STG_B(Bg, 1, 3, t1);
      MM(0, 0); BAR();
      // ph2: buf0 (ih0,kk1); A1.Q1/Q3 <- t1
      RD_B(0, 1); RD_A(0, 0, 1);
      STG_A(Ag, 1, 1, t1); STG_A(Ag, 1, 3, t1);
      MM(0, 1); BAR();
      // ph3: buf0 (ih1,kk0); A0.Q0/Q2 <- t2
      RD_A(0, 1, 0);
      STG_A(Ag, 0, 0, t2); STG_A(Ag, 0, 2, t2);
      MM(1, 0); BAR();
      // ph4: buf0 (ih1,kk1); B0.Q0/Q1 <- t2; counted wait for t1
      RD_A(0, 1, 1);
      STG_B(Bg, 0, 0, t2); STG_B(Bg, 0, 1, t2);
      MM(1, 1); WAITV(4); BAR();
      // ph5: buf1 (ih0,kk0); B0.Q2/Q3 <- t2
      RD_A(1, 0, 0); RD_B(1, 0);
      STG_B(Bg, 0, 2, t2); STG_B(Bg, 0, 3, t2);
      MM(0, 0); BAR();
      // ph6: buf1 (ih0,kk1); A0.Q1/Q3 <- t2
      RD_B(1, 1); RD_A(1, 0, 1);
      STG_A(Ag, 0, 1, t2); STG_A(Ag, 0, 3, t2);
      MM(0, 1); BAR();
      // ph7: buf1 (ih1,kk0); A1.Q0/Q2 <- t3
      RD_A(1, 1, 0);
      STG_A(Ag, 1, 0, t3); STG_A(Ag, 1, 2, t3);
      MM(1, 0); BAR();
      // ph8: buf1 (ih1,kk1); B1.Q0/Q1 <- t3; counted wait for t2
      RD_A(1, 1, 1);
      STG_B(Bg, 1, 0, t3); STG_B(Bg, 1, 1, t3);
      MM(1, 1); WAITV(4); BAR();
    }

    if (r < 2) {
      // ---- Tail with next-tile staging: mirrors a main-loop iteration with
      //      t1=15 (current tile), t2=(next,0), t3=(next,1). Post-state ==
      //      post-prologue state: buf0 = next tile K-tile 0 (drained),
      //      4 loads of next K-tile 1 in flight.
      RD_A(0, 0, 0); RD_B(0, 0);
      STG_B(Bg, 1, 2, 15); STG_B(Bg, 1, 3, 15);
      MM(0, 0); BAR();
      RD_B(0, 1); RD_A(0, 0, 1);
      STG_A(Ag, 1, 1, 15); STG_A(Ag, 1, 3, 15);
      MM(0, 1); BAR();
      RD_A(0, 1, 0);
      STG_A(Ag2, 0, 0, 0); STG_A(Ag2, 0, 2, 0);
      MM(1, 0); BAR();
      RD_A(0, 1, 1);
      STG_B(Bg2, 0, 0, 0); STG_B(Bg2, 0, 1, 0);
      MM(1, 1); WAITV(4); BAR();
      RD_A(1, 0, 0); RD_B(1, 0);
      STG_B(Bg2, 0, 2, 0); STG_B(Bg2, 0, 3, 0);
      MM(0, 0); BAR();
      RD_B(1, 1); RD_A(1, 0, 1);
      STG_A(Ag2, 0, 1, 0); STG_A(Ag2, 0, 3, 0);
      MM(0, 1); BAR();
      RD_A(1, 1, 0);
      STG_A(Ag2, 1, 0, 1); STG_A(Ag2, 1, 2, 1);
      MM(1, 0); BAR();
      RD_A(1, 1, 1);
      STG_B(Bg2, 1, 0, 1); STG_B(Bg2, 1, 1, 1);
      MM(1, 1); WAITV(4); BAR();
    } else {
      // ---- Final tail: no further staging ----
      RD_A(0, 0, 0); RD_B(0, 0);
      STG_B(Bg, 1, 2, 15); STG_B(Bg, 1, 3, 15);
      MM(0, 0); BAR();
      RD_B(0, 1); RD_A(0, 0, 1);
      STG_A(Ag, 1, 1, 15); STG_A(Ag, 1, 3, 15);
      MM(0, 1); BAR();
      RD_A(0, 1, 0); MM(1, 0); BAR();
      RD_A(0, 1, 1); MM(1, 1); WAITV(0); BAR();
      RD_A(1, 0, 0); RD_B(1, 0); MM(0, 0); BAR();
      RD_B(1, 1); RD_A(1, 0, 1); MM(0, 1); BAR();
      RD_A(1, 1, 0); MM(1, 0); BAR();
      RD_A(1, 1, 1); MM(1, 1);
    }

    // ---- Epilogue (register-only + global stores; no LDS -> overlaps the
    //      in-flight next-tile staging; its store drain overlaps next-tile
    //      MFMA).  C/D layout: col=lane&15, row=quad*4+reg (m89/m91). ----
    const int mat = bx >> 2;
    const int ncol0 = (bx & 3) * 256;

    if (mat != 0) {
      unsigned short* Cm = (mat == 1) ? C1p : C2p;
#pragma unroll
      for (int i = 0; i < 8; ++i)
#pragma unroll
        for (int j = 0; j < 4; ++j)
#pragma unroll
          for (int rr = 0; rr < 4; ++rr) {
            int row = mtile0 + wr * 128 + i * 16 + quad * 4 + rr;
            int col = ncol0 + wc * 64 + j * 16 + r16;
            Cm[(size_t)row * HIDDEN + col] = f32_to_bf16(acc[i][j][rr]);
          }
    } else {
      // in-register inclusive cummax over each 32-row subchunk.
      const int bidx = mtile0 >> 12;
      const int sub0 = (mtile0 & 4095) >> 5;
#pragma unroll
      for (int s = 0; s < 4; ++s) {
#pragma unroll
        for (int j = 0; j < 4; ++j) {
          float c0[4], c1[4];
          c0[0] = acc[s * 2][j][0];
          c1[0] = acc[s * 2 + 1][j][0];
#pragma unroll
          for (int rr = 1; rr < 4; ++rr) {
            c0[rr] = fmaxf(c0[rr - 1], acc[s * 2][j][rr]);
            c1[rr] = fmaxf(c1[rr - 1], acc[s * 2 + 1][j][rr]);
          }
          float t0 = c0[3], t1 = c1[3], u;
          // inclusive Hillis-Steele over quads (lane stride 16, same column)
          u = __shfl_up(t0, 16); if (quad >= 1) t0 = fmaxf(t0, u);
          u = __shfl_up(t0, 32); if (quad >= 2) t0 = fmaxf(t0, u);
          u = __shfl_up(t1, 16); if (quad >= 1) t1 = fmaxf(t1, u);
          u = __shfl_up(t1, 32); if (quad >= 2) t1 = fmaxf(t1, u);
          float e0 = __shfl_up(t0, 16); if (quad == 0) e0 = -INFINITY;
          float e1 = __shfl_up(t1, 16); if (quad == 0) e1 = -INFINITY;
          float T0 = __shfl(t0, 48 + r16);   // full total of first 16-row half
          float T1 = __shfl(t1, 48 + r16);
          int col = ncol0 + wc * 64 + j * 16 + r16;
          int rowb = mtile0 + wr * 128 + s * 32 + quad * 4;
#pragma unroll
          for (int rr = 0; rr < 4; ++rr) {
            float L0 = fmaxf(c0[rr], e0);
            float L1 = fmaxf(fmaxf(c1[rr], e1), T0);
            Lp[(size_t)(rowb + rr) * HIDDEN + col] = f32_to_bf16(L0);
            Lp[(size_t)(rowb + 16 + rr) * HIDDEN + col] = f32_to_bf16(L1);
          }
          if (quad == 0) {
            int sub = sub0 + wr * 4 + s;
            cmax[((size_t)bidx * NSUB + sub) * HIDDEN + col] = fmaxf(T0, T1);
          }
        }
      }
    }
  }

#undef STG_A
#undef STG_B
#undef LDA
#undef LDB
#undef RD_A
#undef RD_B
#undef MM
#undef BAR
#undef WAITV
}

// ---- Exclusive prefix-max over subchunks (L2-resident, 2 MB) ----
// Batched loads (16 independent) to hide the ~300cy L2 latency that made
// the naive dependent-chain version latency-bound.
__global__ void prefix_kernel(const float* __restrict__ cmax,
                              float* __restrict__ pmax) {
  int col = blockIdx.x * 256 + threadIdx.x;
  int b = blockIdx.y;
  const float* cp = cmax + (size_t)b * NSUB * HIDDEN + col;
  float* pp = pmax + (size_t)b * NSUB * HIDDEN + col;
  float run = -INFINITY;
#pragma unroll 1
  for (int s0 = 0; s0 < NSUB; s0 += 16) {
    float v[16];
#pragma unroll
    for (int i = 0; i < 16; ++i) v[i] = cp[(size_t)(s0 + i) * HIDDEN];
#pragma unroll
    for (int i = 0; i < 16; ++i) {
      pp[(size_t)(s0 + i) * HIDDEN] = run;
      run = fmaxf(run, v[i]);
    }
  }
}

// ---- Final: pure elementwise, one row per block ----
__global__ void final_kernel(const unsigned short* __restrict__ L,
                             const unsigned short* __restrict__ C1,
                             const unsigned short* __restrict__ C2,
                             const float* __restrict__ pmax,
                             float* __restrict__ out) {
  const int col = threadIdx.x * 4;
  const int s = blockIdx.x;
  const int b = blockIdx.y;
  const int sub = s >> 5;
  float4 p = *(const float4*)(pmax + ((size_t)b * NSUB + sub) * HIDDEN + col);
  size_t base = ((size_t)b * SEQ + s) * HIDDEN + col;
  ushort4 ul = *(const ushort4*)(L + base);
  ushort4 u1 = *(const ushort4*)(C1 + base);
  ushort4 u2 = *(const ushort4*)(C2 + base);
  float m0 = fmaxf(p.x, bf16_to_f32(ul.x));
  float m1 = fmaxf(p.y, bf16_to_f32(ul.y));
  float m2 = fmaxf(p.z, bf16_to_f32(ul.z));
  float m3 = fmaxf(p.w, bf16_to_f32(ul.w));
  float4 o;
  o.x = (m0 + bf16_to_f32(u2.x)) * m0 + bf16_to_f32(u1.x);
  o.y = (m1 + bf16_to_f32(u2.y)) * m1 + bf16_to_f32(u1.y);
  o.z = (m2 + bf16_to_f32(u2.z)) * m2 + bf16_to_f32(u1.z);
  o.w = (m3 + bf16_to_f32(u2.w)) * m3 + bf16_to_f32(u1.w);
  *(float4*)(out + base) = o;
}

extern "C" void kernel_launch(void* const* d_in, const int* in_sizes, int n_in,
                              void* d_out, int out_size, void* d_ws, size_t ws_size,
                              hipStream_t stream) {
  const float* X = (const float*)d_in[0];
  const float* W0 = (const float*)d_in[1];
  const float* W1 = (const float*)d_in[2];
  const float* W2 = (const float*)d_in[3];
  float* out = (float*)d_out;

  // Workspace (~144.7 MiB): Xb, Wb, Lp, C1p, C2p, cmax, pmax
  char* ws = (char*)d_ws;
  unsigned short* Xb = (unsigned short*)ws;
  unsigned short* Wb = (unsigned short*)(ws + 33554432);
  unsigned short* Lp = (unsigned short*)(ws + 33554432 + 6291456);
  unsigned short* C1p = (unsigned short*)(ws + 2 * 33554432 + 6291456);
  unsigned short* C2p = (unsigned short*)(ws + 3 * 33554432 + 6291456);
  float* cmax = (float*)(ws + 4 * 33554432 + 6291456);
  float* pmax = (float*)(ws + 4 * 33554432 + 6291456 + 2097152);

  convert_kernel<<<19456, 256, 0, stream>>>(X, W0, W1, W2, Xb, Wb);

  // Persistent: 256 blocks (1/CU), 3 tiles each (768 logical tiles,
  // XCD-swizzled inside the kernel)
  gemm256_kernel<<<256, 512, 131072, stream>>>((const bf16_t*)Xb, (const bf16_t*)Wb,
                                               Lp, C1p, C2p, cmax);

  dim3 pgrid(4, BATCH);
  prefix_kernel<<<pgrid, 256, 0, stream>>>(cmax, pmax);

  dim3 fgrid(SEQ, BATCH);
  final_kernel<<<fgrid, 256, 0, stream>>>(Lp, C1p, C2p, pmax, out);
}

// Round 3
// 158.936 us; speedup vs baseline: 1.9087x; 1.9087x over previous
//
#include <hip/hip_runtime.h>
#include <cstdint>
#include <cstddef>

#define HIDDEN 1024
#define BATCH 4
#define SEQ 4096
#define M_ROWS (BATCH * SEQ)   // 16384
#define K_DIM 1024
#define SUBCHUNK 32
#define NSUB (SEQ / SUBCHUNK)  // 128

typedef __bf16 bf16_t;
typedef __bf16 v8bf __attribute__((ext_vector_type(8)));
typedef float v4f __attribute__((ext_vector_type(4)));
typedef unsigned short us8 __attribute__((ext_vector_type(8)));

__device__ __forceinline__ unsigned short f32_to_bf16(float f) {
  unsigned int u = __float_as_uint(f);
  u += 0x7fffu + ((u >> 16) & 1u);   // round-to-nearest-even
  return (unsigned short)(u >> 16);
}
__device__ __forceinline__ float bf16_to_f32(unsigned short u) {
  return __uint_as_float((unsigned int)u << 16);
}

// ---- Merged convert: X fp32->bf16 (blocks 0..16383) and
//      Wb = (W0+W1)/8 | W1 | W2 as bf16 (blocks 16384..19455) ----
__global__ void convert_kernel(const float* __restrict__ X,
                               const float* __restrict__ W0,
                               const float* __restrict__ W1,
                               const float* __restrict__ W2,
                               unsigned short* __restrict__ Xb,
                               unsigned short* __restrict__ Wb) {
  int bx = blockIdx.x;
  if (bx < 16384) {
    int i = bx * 256 + threadIdx.x;        // over 4,194,304 float4s (exact)
    float4 f = ((const float4*)X)[i];
    ushort4 u;
    u.x = f32_to_bf16(f.x); u.y = f32_to_bf16(f.y);
    u.z = f32_to_bf16(f.z); u.w = f32_to_bf16(f.w);
    ((ushort4*)Xb)[i] = u;
  } else {
    int i = (bx - 16384) * 256 + threadIdx.x;  // over 786,432 float4s (exact)
    int mat = i >> 18;                          // 262,144 float4 per matrix
    int off = i & 0x3FFFF;
    float4 f;
    if (mat == 0) {
      float4 a = ((const float4*)W0)[off];
      float4 b = ((const float4*)W1)[off];
      f.x = (a.x + b.x) * 0.125f; f.y = (a.y + b.y) * 0.125f;
      f.z = (a.z + b.z) * 0.125f; f.w = (a.w + b.w) * 0.125f;
    } else {
      const float* src = (mat == 1) ? W1 : W2;
      f = ((const float4*)src)[off];
    }
    ushort4 u;
    u.x = f32_to_bf16(f.x); u.y = f32_to_bf16(f.y);
    u.z = f32_to_bf16(f.z); u.w = f32_to_bf16(f.w);
    ((ushort4*)Wb)[i] = u;
  }
}

// ---- bf16 GEMM, 256x256 tile, BK=64, 8 waves (2Mx4N), 8-phase schedule
// with counted vmcnt (T3+T4), setprio around MFMA bursts (T5), k-chunk XOR
// LDS swizzle (conflict-free, both-sides: pre-swizzled global source +
// swizzled ds_read), XCD-swizzled block mapping (T1).
// NOTE (R2 lesson): the epilogue store burst MUST stay at block end,
// immediately before exit — spreading the 32B store chunks over time
// collapses L2 write-combining (WRITE_SIZE 100->466 MB, RMW fetch 94->290).
// C[m][n] = sum_k A[m][k]*B[n][k];  A:[16384][1024], B:[3072][1024] (B^T).
// mat==0 blocks run fused in-subchunk-cummax epilogue; mat 1/2 store C1/C2.
// LDS: 128 KiB dynamic = 2 dbuf x (A 256x64 + B 256x64) bf16.
__global__ __launch_bounds__(512, 2) void gemm256_kernel(
    const bf16_t* __restrict__ A, const bf16_t* __restrict__ B,
    unsigned short* __restrict__ Lp, unsigned short* __restrict__ C1p,
    unsigned short* __restrict__ C2p, float* __restrict__ cmax) {
  extern __shared__ __align__(16) char smem[];   // 131072 B

  const int tid = threadIdx.x;
  const int wave = tid >> 6;     // 0..7
  const int lane = tid & 63;
  const int quad = lane >> 4;    // 0..3
  const int r16 = lane & 15;
  const int wr = wave >> 2;      // 0..1 -> 128-row half
  const int wc = wave & 3;       // 0..3 -> 64-col quarter

  // Bijective XCD swizzle: 768 blocks = 8 XCDs x 96; XCD k gets m-tiles [8k,8k+8)
  const int orig = (int)blockIdx.x;
  const int swz = (orig & 7) * 96 + (orig >> 3);
  const int bx = swz % 12;       // n-tile (12 = 3 matrices x 4 tiles)
  const int mt = swz / 12;       // m-tile (64)
  const int mtile0 = mt * 256;
  const int nbase = bx * 256;

  // Staging: LDS dest is linear (base + lane*16); swizzle applied on the
  // GLOBAL source address. LDS slot (row m, 16B-chunk c) holds global
  // k-chunk c ^ (m&7).  Lane l covers row (+l>>3), chunk l&7 -> source
  // chunk (l&7)^(l>>3).
  const int l3 = lane >> 3;
  const int lc = lane & 7;
  const size_t laneOff = (size_t)l3 * K_DIM + (size_t)((lc ^ l3) << 3);
  const bf16_t* Ag = A + (size_t)(mtile0 + wave * 8) * K_DIM + laneOff;
  const bf16_t* Bg = B + (size_t)(nbase + wave * 8) * K_DIM + laneOff;

  // ds_read addressing: row m = wr*128 + i*16 + r16 (A) / wc*64 + j*16 + r16 (B),
  // desired chunk kk*4+quad stored at chunk (kk*4+quad)^(r16&7).
  const int aRow = (wr * 128 + r16) * 128;   // bytes (row stride 128B)
  const int bRow = (wc * 64 + r16) * 128;
  const int cxor = (r16 & 7) * 16;
  const int qx = quad * 16;

  v4f acc[8][4];
#pragma unroll
  for (int i = 0; i < 8; ++i)
#pragma unroll
    for (int j = 0; j < 4; ++j) acc[i][j] = (v4f)(0.0f);

  v8bf afr[4];
  v8bf bfr[4][2];

#define STG_A(d, q, kt) __builtin_amdgcn_global_load_lds( \
    (__attribute__((address_space(1))) void*)(Ag + (size_t)(q) * (64 * K_DIM) + (size_t)(kt) * 64), \
    (__attribute__((address_space(3))) void*)(smem + (d) * 32768 + (q) * 8192 + wave * 1024), 16, 0, 0)
#define STG_B(d, q, kt) __builtin_amdgcn_global_load_lds( \
    (__attribute__((address_space(1))) void*)(Bg + (size_t)(q) * (64 * K_DIM) + (size_t)(kt) * 64), \
    (__attribute__((address_space(3))) void*)(smem + 65536 + (d) * 32768 + (q) * 8192 + wave * 1024), 16, 0, 0)
#define LDA(d, i, kk) (*(const v8bf*)(smem + (d) * 32768 + aRow + (i) * 2048 + (((kk) * 64 + qx) ^ cxor)))
#define LDB(d, j, kk) (*(const v8bf*)(smem + 65536 + (d) * 32768 + bRow + (j) * 2048 + (((kk) * 64 + qx) ^ cxor)))
#define RD_A(d, ih, kk) { _Pragma("unroll") for (int ii = 0; ii < 4; ++ii) afr[ii] = LDA(d, (ih) * 4 + ii, kk); }
#define RD_B(d, kk) { _Pragma("unroll") for (int j = 0; j < 4; ++j) bfr[j][kk] = LDB(d, j, kk); }
#define MM(ih, kk) \
  __builtin_amdgcn_s_barrier(); \
  asm volatile("s_waitcnt lgkmcnt(0)" ::: "memory"); \
  __builtin_amdgcn_s_setprio(1); \
  { _Pragma("unroll") for (int ii = 0; ii < 4; ++ii) { _Pragma("unroll") for (int j = 0; j < 4; ++j) \
      acc[(ih) * 4 + ii][j] = __builtin_amdgcn_mfma_f32_16x16x32_bf16(afr[ii], bfr[j][(kk)], acc[(ih) * 4 + ii][j], 0, 0, 0); } } \
  __builtin_amdgcn_s_setprio(0);
#define BAR() __builtin_amdgcn_s_barrier()
#define WAITV(n) asm volatile("s_waitcnt vmcnt(" #n ")" ::: "memory")

  // ---- Prologue: tile0 full -> buf0 (8 oldest), tile1 partial -> buf1 (4) ----
  STG_A(0, 0, 0); STG_A(0, 1, 0); STG_A(0, 2, 0); STG_A(0, 3, 0);
  STG_B(0, 0, 0); STG_B(0, 1, 0); STG_B(0, 2, 0); STG_B(0, 3, 0);
  STG_A(1, 0, 1); STG_A(1, 2, 1); STG_B(1, 0, 1); STG_B(1, 1, 1);
  WAITV(4);                    // drain tile0's 8; leave tile1's 4 in flight
  BAR();

  // ---- Main loop: iter computes tiles 2it (buf0), 2it+1 (buf1);
  //      stages 2it+1 remainder, 2it+2 (buf0), 2it+3 (buf1 start). ----
  for (int it = 0; it < 7; ++it) {
    const int t1 = 2 * it + 1, t2 = t1 + 1, t3 = t1 + 2;
    // ph1: buf0 (ih0,kk0); B1.Q2/Q3 <- t1
    RD_A(0, 0, 0); RD_B(0, 0);
    STG_B(1, 2, t1); STG_B(1, 3, t1);
    MM(0, 0); BAR();
    // ph2: buf0 (ih0,kk1); A1.Q1/Q3 <- t1
    RD_B(0, 1); RD_A(0, 0, 1);
    STG_A(1, 1, t1); STG_A(1, 3, t1);
    MM(0, 1); BAR();
    // ph3: buf0 (ih1,kk0); A0.Q0/Q2 <- t2
    RD_A(0, 1, 0);
    STG_A(0, 0, t2); STG_A(0, 2, t2);
    MM(1, 0); BAR();
    // ph4: buf0 (ih1,kk1); B0.Q0/Q1 <- t2; counted wait for tile t1
    RD_A(0, 1, 1);
    STG_B(0, 0, t2); STG_B(0, 1, t2);
    MM(1, 1); WAITV(4); BAR();
    // ph5: buf1 (ih0,kk0); B0.Q2/Q3 <- t2
    RD_A(1, 0, 0); RD_B(1, 0);
    STG_B(0, 2, t2); STG_B(0, 3, t2);
    MM(0, 0); BAR();
    // ph6: buf1 (ih0,kk1); A0.Q1/Q3 <- t2
    RD_B(1, 1); RD_A(1, 0, 1);
    STG_A(0, 1, t2); STG_A(0, 3, t2);
    MM(0, 1); BAR();
    // ph7: buf1 (ih1,kk0); A1.Q0/Q2 <- t3
    RD_A(1, 1, 0);
    STG_A(1, 0, t3); STG_A(1, 2, t3);
    MM(1, 0); BAR();
    // ph8: buf1 (ih1,kk1); B1.Q0/Q1 <- t3; counted wait for tile t2
    RD_A(1, 1, 1);
    STG_B(1, 0, t3); STG_B(1, 1, t3);
    MM(1, 1); WAITV(4); BAR();
  }
  // ---- Tail (it = 7): tiles 14 (buf0), 15 (buf1); only t1=15 staging ----
  RD_A(0, 0, 0); RD_B(0, 0);
  STG_B(1, 2, 15); STG_B(1, 3, 15);
  MM(0, 0); BAR();
  RD_B(0, 1); RD_A(0, 0, 1);
  STG_A(1, 1, 15); STG_A(1, 3, 15);
  MM(0, 1); BAR();
  RD_A(0, 1, 0); MM(1, 0); BAR();
  RD_A(0, 1, 1); MM(1, 1); WAITV(0); BAR();
  RD_A(1, 0, 0); RD_B(1, 0); MM(0, 0); BAR();
  RD_B(1, 1); RD_A(1, 0, 1); MM(0, 1); BAR();
  RD_A(1, 1, 0); MM(1, 0); BAR();
  RD_A(1, 1, 1); MM(1, 1);

#undef STG_A
#undef STG_B
#undef LDA
#undef LDB
#undef RD_A
#undef RD_B
#undef MM
#undef BAR
#undef WAITV

  // ---- Epilogue. C/D layout: col=lane&15, row=quad*4+reg (m89/m91). ----
  const int mat = bx >> 2;
  const int ncol0 = (bx & 3) * 256;

  if (mat != 0) {
    unsigned short* Cm = (mat == 1) ? C1p : C2p;
#pragma unroll
    for (int i = 0; i < 8; ++i)
#pragma unroll
      for (int j = 0; j < 4; ++j)
#pragma unroll
        for (int r = 0; r < 4; ++r) {
          int row = mtile0 + wr * 128 + i * 16 + quad * 4 + r;
          int col = ncol0 + wc * 64 + j * 16 + r16;
          Cm[(size_t)row * HIDDEN + col] = f32_to_bf16(acc[i][j][r]);
        }
    return;
  }

  // mat==0: in-register inclusive cummax over each 32-row subchunk.
  // Wave owns 128 rows = 4 subchunks; subchunk s covers acc i=2s,2s+1.
  const int bidx = mtile0 >> 12;
  const int sub0 = (mtile0 & 4095) >> 5;
#pragma unroll
  for (int s = 0; s < 4; ++s) {
#pragma unroll
    for (int j = 0; j < 4; ++j) {
      float c0[4], c1[4];
      c0[0] = acc[s * 2][j][0];
      c1[0] = acc[s * 2 + 1][j][0];
#pragma unroll
      for (int r = 1; r < 4; ++r) {
        c0[r] = fmaxf(c0[r - 1], acc[s * 2][j][r]);
        c1[r] = fmaxf(c1[r - 1], acc[s * 2 + 1][j][r]);
      }
      float t0 = c0[3], t1 = c1[3], u;
      // inclusive Hillis-Steele over quads (lane stride 16, same column)
      u = __shfl_up(t0, 16); if (quad >= 1) t0 = fmaxf(t0, u);
      u = __shfl_up(t0, 32); if (quad >= 2) t0 = fmaxf(t0, u);
      u = __shfl_up(t1, 16); if (quad >= 1) t1 = fmaxf(t1, u);
      u = __shfl_up(t1, 32); if (quad >= 2) t1 = fmaxf(t1, u);
      float e0 = __shfl_up(t0, 16); if (quad == 0) e0 = -INFINITY;
      float e1 = __shfl_up(t1, 16); if (quad == 0) e1 = -INFINITY;
      float T0 = __shfl(t0, 48 + r16);   // full total of first 16-row half
      float T1 = __shfl(t1, 48 + r16);
      int col = ncol0 + wc * 64 + j * 16 + r16;
      int rowb = mtile0 + wr * 128 + s * 32 + quad * 4;
#pragma unroll
      for (int r = 0; r < 4; ++r) {
        float L0 = fmaxf(c0[r], e0);
        float L1 = fmaxf(fmaxf(c1[r], e1), T0);
        Lp[(size_t)(rowb + r) * HIDDEN + col] = f32_to_bf16(L0);
        Lp[(size_t)(rowb + 16 + r) * HIDDEN + col] = f32_to_bf16(L1);
      }
      if (quad == 0) {
        int sub = sub0 + wr * 4 + s;
        cmax[((size_t)bidx * NSUB + sub) * HIDDEN + col] = fmaxf(T0, T1);
      }
    }
  }
}

// ---- Exclusive prefix-max over subchunks (L2-resident, 2 MB) ----
// Batched loads (16 independent per round) to hide the ~300cy latency of
// the naive 128-step dependent chain.
__global__ void prefix_kernel(const float* __restrict__ cmax,
                              float* __restrict__ pmax) {
  int col = blockIdx.x * 256 + threadIdx.x;
  int b = blockIdx.y;
  const float* cp = cmax + (size_t)b * NSUB * HIDDEN + col;
  float* pp = pmax + (size_t)b * NSUB * HIDDEN + col;
  float run = -INFINITY;
#pragma unroll 1
  for (int s0 = 0; s0 < NSUB; s0 += 16) {
    float v[16];
#pragma unroll
    for (int i = 0; i < 16; ++i) v[i] = cp[(size_t)(s0 + i) * HIDDEN];
#pragma unroll
    for (int i = 0; i < 16; ++i) {
      pp[(size_t)(s0 + i) * HIDDEN] = run;
      run = fmaxf(run, v[i]);
    }
  }
}

// ---- Final: pure elementwise. 16B loads, 2 rows per block.
// grid (2048, 4), block 256: threads 0..127 -> row 2s, 128..255 -> row 2s+1,
// 8 cols/thread.  Rows 2s and 2s+1 always share a subchunk (32-row chunks).
__global__ void final_kernel(const unsigned short* __restrict__ L,
                             const unsigned short* __restrict__ C1,
                             const unsigned short* __restrict__ C2,
                             const float* __restrict__ pmax,
                             float* __restrict__ out) {
  const int t = threadIdx.x;
  const int half = t >> 7;
  const int col = (t & 127) * 8;
  const int s = blockIdx.x * 2 + half;
  const int b = blockIdx.y;
  const int sub = s >> 5;
  const float* pv = pmax + ((size_t)b * NSUB + sub) * HIDDEN + col;
  float4 p0 = *(const float4*)pv;
  float4 p1 = *(const float4*)(pv + 4);
  float pr[8] = {p0.x, p0.y, p0.z, p0.w, p1.x, p1.y, p1.z, p1.w};
  size_t base = ((size_t)b * SEQ + s) * HIDDEN + col;
  us8 ul = *(const us8*)(L + base);
  us8 u1 = *(const us8*)(C1 + base);
  us8 u2 = *(const us8*)(C2 + base);
  float o[8];
#pragma unroll
  for (int k = 0; k < 8; ++k) {
    float m = fmaxf(pr[k], bf16_to_f32((unsigned short)ul[k]));
    o[k] = (m + bf16_to_f32((unsigned short)u2[k])) * m
           + bf16_to_f32((unsigned short)u1[k]);
  }
  float4 o0 = {o[0], o[1], o[2], o[3]};
  float4 o1 = {o[4], o[5], o[6], o[7]};
  *(float4*)(out + base) = o0;
  *(float4*)(out + base + 4) = o1;
}

extern "C" void kernel_launch(void* const* d_in, const int* in_sizes, int n_in,
                              void* d_out, int out_size, void* d_ws, size_t ws_size,
                              hipStream_t stream) {
  const float* X = (const float*)d_in[0];
  const float* W0 = (const float*)d_in[1];
  const float* W1 = (const float*)d_in[2];
  const float* W2 = (const float*)d_in[3];
  float* out = (float*)d_out;

  // Workspace (~144.7 MiB): Xb, Wb, Lp, C1p, C2p, cmax, pmax
  char* ws = (char*)d_ws;
  unsigned short* Xb = (unsigned short*)ws;
  unsigned short* Wb = (unsigned short*)(ws + 33554432);
  unsigned short* Lp = (unsigned short*)(ws + 33554432 + 6291456);
  unsigned short* C1p = (unsigned short*)(ws + 2 * 33554432 + 6291456);
  unsigned short* C2p = (unsigned short*)(ws + 3 * 33554432 + 6291456);
  float* cmax = (float*)(ws + 4 * 33554432 + 6291456);
  float* pmax = (float*)(ws + 4 * 33554432 + 6291456 + 2097152);

  convert_kernel<<<19456, 256, 0, stream>>>(X, W0, W1, W2, Xb, Wb);

  // 12 n-tiles x 64 m-tiles = 768 blocks (XCD-swizzled inside the kernel)
  gemm256_kernel<<<768, 512, 131072, stream>>>((const bf16_t*)Xb, (const bf16_t*)Wb,
                                               Lp, C1p, C2p, cmax);

  dim3 pgrid(4, BATCH);
  prefix_kernel<<<pgrid, 256, 0, stream>>>(cmax, pmax);

  dim3 fgrid(SEQ / 2, BATCH);
  final_kernel<<<fgrid, 256, 0, stream>>>(Lp, C1p, C2p, pmax, out);
}

// Round 4
// 131.070 us; speedup vs baseline: 2.3146x; 1.2126x over previous
//
#include <hip/hip_runtime.h>
#include <cstdint>
#include <cstddef>

#define HIDDEN 1024
#define BATCH 4
#define SEQ 4096
#define M_ROWS (BATCH * SEQ)   // 16384
#define K_DIM 1024
#define SUBCHUNK 32
#define NSUB (SEQ / SUBCHUNK)  // 128

typedef __bf16 bf16_t;
typedef __bf16 v8bf __attribute__((ext_vector_type(8)));
typedef float v4f __attribute__((ext_vector_type(4)));
typedef unsigned short us8 __attribute__((ext_vector_type(8)));

__device__ __forceinline__ unsigned short f32_to_bf16(float f) {
  unsigned int u = __float_as_uint(f);
  u += 0x7fffu + ((u >> 16) & 1u);   // round-to-nearest-even
  return (unsigned short)(u >> 16);
}
__device__ __forceinline__ float bf16_to_f32(unsigned short u) {
  return __uint_as_float((unsigned int)u << 16);
}

// ---- Merged convert: X fp32->bf16 (blocks 0..16383) and
//      Wb = (W0+W1)/8 | W1 | W2 as bf16 (blocks 16384..19455) ----
__global__ void convert_kernel(const float* __restrict__ X,
                               const float* __restrict__ W0,
                               const float* __restrict__ W1,
                               const float* __restrict__ W2,
                               unsigned short* __restrict__ Xb,
                               unsigned short* __restrict__ Wb) {
  int bx = blockIdx.x;
  if (bx < 16384) {
    int i = bx * 256 + threadIdx.x;        // over 4,194,304 float4s (exact)
    float4 f = ((const float4*)X)[i];
    ushort4 u;
    u.x = f32_to_bf16(f.x); u.y = f32_to_bf16(f.y);
    u.z = f32_to_bf16(f.z); u.w = f32_to_bf16(f.w);
    ((ushort4*)Xb)[i] = u;
  } else {
    int i = (bx - 16384) * 256 + threadIdx.x;  // over 786,432 float4s (exact)
    int mat = i >> 18;                          // 262,144 float4 per matrix
    int off = i & 0x3FFFF;
    float4 f;
    if (mat == 0) {
      float4 a = ((const float4*)W0)[off];
      float4 b = ((const float4*)W1)[off];
      f.x = (a.x + b.x) * 0.125f; f.y = (a.y + b.y) * 0.125f;
      f.z = (a.z + b.z) * 0.125f; f.w = (a.w + b.w) * 0.125f;
    } else {
      const float* src = (mat == 1) ? W1 : W2;
      f = ((const float4*)src)[off];
    }
    ushort4 u;
    u.x = f32_to_bf16(f.x); u.y = f32_to_bf16(f.y);
    u.z = f32_to_bf16(f.z); u.w = f32_to_bf16(f.w);
    ((ushort4*)Wb)[i] = u;
  }
}

// ============================================================================
// gemm_s: S = X @ W01^T (mat0 only), 256x256 tile, BK=64, 8 waves (2Mx4N),
// 8-phase counted-vmcnt schedule, fused in-subchunk-cummax epilogue.
// 256 blocks (1 round).  Identical loop structure to the verified R3 kernel.
// ============================================================================
__global__ __launch_bounds__(512, 2) void gemm_s_kernel(
    const bf16_t* __restrict__ A, const bf16_t* __restrict__ B,
    unsigned short* __restrict__ Lp, float* __restrict__ cmax) {
  extern __shared__ __align__(16) char smem[];   // 131072 B

  const int tid = threadIdx.x;
  const int wave = tid >> 6;     // 0..7
  const int lane = tid & 63;
  const int quad = lane >> 4;    // 0..3
  const int r16 = lane & 15;
  const int wr = wave >> 2;      // 0..1 -> 128-row half
  const int wc = wave & 3;       // 0..3 -> 64-col quarter

  // Bijective XCD swizzle: 256 blocks = 8 XCDs x 32
  const int orig = (int)blockIdx.x;
  const int swz = (orig & 7) * 32 + (orig >> 3);
  const int bx = swz & 3;        // n-tile (4)
  const int mt = swz >> 2;       // m-tile (64)
  const int mtile0 = mt * 256;
  const int nbase = bx * 256;    // W01 rows 0..1023

  // Staging: LDS dest linear; swizzle on GLOBAL source.  LDS slot (row m,
  // 16B-chunk c) holds global k-chunk c ^ (m&7).
  const int l3 = lane >> 3;
  const int lc = lane & 7;
  const size_t laneOff = (size_t)l3 * K_DIM + (size_t)((lc ^ l3) << 3);
  const bf16_t* Ag = A + (size_t)(mtile0 + wave * 8) * K_DIM + laneOff;
  const bf16_t* Bg = B + (size_t)(nbase + wave * 8) * K_DIM + laneOff;

  const int aRow = (wr * 128 + r16) * 128;   // bytes (row stride 128B)
  const int bRow = (wc * 64 + r16) * 128;
  const int cxor = (r16 & 7) * 16;
  const int qx = quad * 16;

  v4f acc[8][4];
#pragma unroll
  for (int i = 0; i < 8; ++i)
#pragma unroll
    for (int j = 0; j < 4; ++j) acc[i][j] = (v4f)(0.0f);

  v8bf afr[4];
  v8bf bfr[4][2];

#define STG_A(d, q, kt) __builtin_amdgcn_global_load_lds( \
    (__attribute__((address_space(1))) void*)(Ag + (size_t)(q) * (64 * K_DIM) + (size_t)(kt) * 64), \
    (__attribute__((address_space(3))) void*)(smem + (d) * 32768 + (q) * 8192 + wave * 1024), 16, 0, 0)
#define STG_B(d, q, kt) __builtin_amdgcn_global_load_lds( \
    (__attribute__((address_space(1))) void*)(Bg + (size_t)(q) * (64 * K_DIM) + (size_t)(kt) * 64), \
    (__attribute__((address_space(3))) void*)(smem + 65536 + (d) * 32768 + (q) * 8192 + wave * 1024), 16, 0, 0)
#define LDA(d, i, kk) (*(const v8bf*)(smem + (d) * 32768 + aRow + (i) * 2048 + (((kk) * 64 + qx) ^ cxor)))
#define LDB(d, j, kk) (*(const v8bf*)(smem + 65536 + (d) * 32768 + bRow + (j) * 2048 + (((kk) * 64 + qx) ^ cxor)))
#define RD_A(d, ih, kk) { _Pragma("unroll") for (int ii = 0; ii < 4; ++ii) afr[ii] = LDA(d, (ih) * 4 + ii, kk); }
#define RD_B(d, kk) { _Pragma("unroll") for (int j = 0; j < 4; ++j) bfr[j][kk] = LDB(d, j, kk); }
#define MM(ih, kk) \
  __builtin_amdgcn_s_barrier(); \
  asm volatile("s_waitcnt lgkmcnt(0)" ::: "memory"); \
  __builtin_amdgcn_s_setprio(1); \
  { _Pragma("unroll") for (int ii = 0; ii < 4; ++ii) { _Pragma("unroll") for (int j = 0; j < 4; ++j) \
      acc[(ih) * 4 + ii][j] = __builtin_amdgcn_mfma_f32_16x16x32_bf16(afr[ii], bfr[j][(kk)], acc[(ih) * 4 + ii][j], 0, 0, 0); } } \
  __builtin_amdgcn_s_setprio(0);
#define BAR() __builtin_amdgcn_s_barrier()
#define WAITV(n) asm volatile("s_waitcnt vmcnt(" #n ")" ::: "memory")

  // ---- Prologue: tile0 full -> buf0 (8 oldest), tile1 partial -> buf1 (4) ----
  STG_A(0, 0, 0); STG_A(0, 1, 0); STG_A(0, 2, 0); STG_A(0, 3, 0);
  STG_B(0, 0, 0); STG_B(0, 1, 0); STG_B(0, 2, 0); STG_B(0, 3, 0);
  STG_A(1, 0, 1); STG_A(1, 2, 1); STG_B(1, 0, 1); STG_B(1, 1, 1);
  WAITV(4);
  BAR();

  for (int it = 0; it < 7; ++it) {
    const int t1 = 2 * it + 1, t2 = t1 + 1, t3 = t1 + 2;
    RD_A(0, 0, 0); RD_B(0, 0);
    STG_B(1, 2, t1); STG_B(1, 3, t1);
    MM(0, 0); BAR();
    RD_B(0, 1); RD_A(0, 0, 1);
    STG_A(1, 1, t1); STG_A(1, 3, t1);
    MM(0, 1); BAR();
    RD_A(0, 1, 0);
    STG_A(0, 0, t2); STG_A(0, 2, t2);
    MM(1, 0); BAR();
    RD_A(0, 1, 1);
    STG_B(0, 0, t2); STG_B(0, 1, t2);
    MM(1, 1); WAITV(4); BAR();
    RD_A(1, 0, 0); RD_B(1, 0);
    STG_B(0, 2, t2); STG_B(0, 3, t2);
    MM(0, 0); BAR();
    RD_B(1, 1); RD_A(1, 0, 1);
    STG_A(0, 1, t2); STG_A(0, 3, t2);
    MM(0, 1); BAR();
    RD_A(1, 1, 0);
    STG_A(1, 0, t3); STG_A(1, 2, t3);
    MM(1, 0); BAR();
    RD_A(1, 1, 1);
    STG_B(1, 0, t3); STG_B(1, 1, t3);
    MM(1, 1); WAITV(4); BAR();
  }
  // ---- Tail: tiles 14 (buf0), 15 (buf1) ----
  RD_A(0, 0, 0); RD_B(0, 0);
  STG_B(1, 2, 15); STG_B(1, 3, 15);
  MM(0, 0); BAR();
  RD_B(0, 1); RD_A(0, 0, 1);
  STG_A(1, 1, 15); STG_A(1, 3, 15);
  MM(0, 1); BAR();
  RD_A(0, 1, 0); MM(1, 0); BAR();
  RD_A(0, 1, 1); MM(1, 1); WAITV(0); BAR();
  RD_A(1, 0, 0); RD_B(1, 0); MM(0, 0); BAR();
  RD_B(1, 1); RD_A(1, 0, 1); MM(0, 1); BAR();
  RD_A(1, 1, 0); MM(1, 0); BAR();
  RD_A(1, 1, 1); MM(1, 1);

#undef STG_A
#undef STG_B
#undef LDA
#undef LDB
#undef RD_A
#undef RD_B
#undef MM
#undef BAR
#undef WAITV

  // ---- Fused cummax epilogue (compact store burst at block exit).
  // C/D layout: col=lane&15, row=quad*4+reg (m89/m91). ----
  const int ncol0 = bx * 256;
  const int bidx = mtile0 >> 12;
  const int sub0 = (mtile0 & 4095) >> 5;
#pragma unroll
  for (int s = 0; s < 4; ++s) {
#pragma unroll
    for (int j = 0; j < 4; ++j) {
      float c0[4], c1[4];
      c0[0] = acc[s * 2][j][0];
      c1[0] = acc[s * 2 + 1][j][0];
#pragma unroll
      for (int r = 1; r < 4; ++r) {
        c0[r] = fmaxf(c0[r - 1], acc[s * 2][j][r]);
        c1[r] = fmaxf(c1[r - 1], acc[s * 2 + 1][j][r]);
      }
      float t0 = c0[3], t1 = c1[3], u;
      u = __shfl_up(t0, 16); if (quad >= 1) t0 = fmaxf(t0, u);
      u = __shfl_up(t0, 32); if (quad >= 2) t0 = fmaxf(t0, u);
      u = __shfl_up(t1, 16); if (quad >= 1) t1 = fmaxf(t1, u);
      u = __shfl_up(t1, 32); if (quad >= 2) t1 = fmaxf(t1, u);
      float e0 = __shfl_up(t0, 16); if (quad == 0) e0 = -INFINITY;
      float e1 = __shfl_up(t1, 16); if (quad == 0) e1 = -INFINITY;
      float T0 = __shfl(t0, 48 + r16);
      float T1 = __shfl(t1, 48 + r16);
      int col = ncol0 + wc * 64 + j * 16 + r16;
      int rowb = mtile0 + wr * 128 + s * 32 + quad * 4;
#pragma unroll
      for (int r = 0; r < 4; ++r) {
        float L0 = fmaxf(c0[r], e0);
        float L1 = fmaxf(fmaxf(c1[r], e1), T0);
        Lp[(size_t)(rowb + r) * HIDDEN + col] = f32_to_bf16(L0);
        Lp[(size_t)(rowb + 16 + r) * HIDDEN + col] = f32_to_bf16(L1);
      }
      if (quad == 0) {
        int sub = sub0 + wr * 4 + s;
        cmax[((size_t)bidx * NSUB + sub) * HIDDEN + col] = fmaxf(T0, T1);
      }
    }
  }
}

// ---- Exclusive prefix-max over subchunks (L2-resident, 2 MB) ----
__global__ void prefix_kernel(const float* __restrict__ cmax,
                              float* __restrict__ pmax) {
  int col = blockIdx.x * 256 + threadIdx.x;
  int b = blockIdx.y;
  const float* cp = cmax + (size_t)b * NSUB * HIDDEN + col;
  float* pp = pmax + (size_t)b * NSUB * HIDDEN + col;
  float run = -INFINITY;
#pragma unroll 1
  for (int s0 = 0; s0 < NSUB; s0 += 16) {
    float v[16];
#pragma unroll
    for (int i = 0; i < 16; ++i) v[i] = cp[(size_t)(s0 + i) * HIDDEN];
#pragma unroll
    for (int i = 0; i < 16; ++i) {
      pp[(size_t)(s0 + i) * HIDDEN] = run;
      run = fmaxf(run, v[i]);
    }
  }
}

// ============================================================================
// gemm_f: dual GEMM C1 = X@W1^T, C2 = X@W2^T for the SAME 256x128 output
// region, with fused final epilogue: out = (max(pmax,L)+c2)*max(pmax,L)+c1.
// C1/C2 never hit memory; final_kernel eliminated.
// 512 blocks, 8 waves as 2M x 4N(32-col); acc1[8][2]+acc2[8][2] = 128 VGPR.
// Same 8-phase counted-vmcnt schedule: per K-tile 8 staging loads
// (A:4, B1:2, B2:2), GEMM1's B-quarters {0,1,2,3} -> {B1q0,B1q1,B2q0,B2q1};
// A-quarter hazard structure (ih0 reads q0,q2; ih1 reads q1,q3) identical.
// LDS: per buffer A 32K + B1 16K + B2 16K = 64K, x2 = 128 KiB.
// ============================================================================
__global__ __launch_bounds__(512, 2) void gemm_f_kernel(
    const bf16_t* __restrict__ A, const bf16_t* __restrict__ B,
    const unsigned short* __restrict__ Lp, const float* __restrict__ pmax,
    float* __restrict__ out) {
  extern __shared__ __align__(16) char smem[];   // 131072 B

  const int tid = threadIdx.x;
  const int wave = tid >> 6;     // 0..7
  const int lane = tid & 63;
  const int quad = lane >> 4;
  const int r16 = lane & 15;
  const int wr = wave >> 2;      // 0..1 -> 128-row half
  const int wc = wave & 3;       // 0..3 -> 32-col quarter

  // Bijective XCD swizzle: 512 blocks = 8 XCDs x 64; contiguous m per XCD
  const int orig = (int)blockIdx.x;
  const int swz = (orig & 7) * 64 + (orig >> 3);
  const int mt = swz >> 3;       // 0..63
  const int nt = swz & 7;        // 0..7
  const int mtile0 = mt * 256;
  const int ncol0 = nt * 128;

  const int l3 = lane >> 3;
  const int lc = lane & 7;
  const size_t laneOff = (size_t)l3 * K_DIM + (size_t)((lc ^ l3) << 3);
  const bf16_t* Ag = A + (size_t)(mtile0 + wave * 8) * K_DIM + laneOff;
  const bf16_t* Bg1 = B + (size_t)(1024 + ncol0 + wave * 8) * K_DIM + laneOff;
  const bf16_t* Bg2 = B + (size_t)(2048 + ncol0 + wave * 8) * K_DIM + laneOff;

  const int aRow = (wr * 128 + r16) * 128;   // bytes
  const int bRow = (wc * 32 + r16) * 128;    // within 128-row B panel
  const int cxor = (r16 & 7) * 16;
  const int qx = quad * 16;

  v4f acc1[8][2], acc2[8][2];
#pragma unroll
  for (int i = 0; i < 8; ++i)
#pragma unroll
    for (int j = 0; j < 2; ++j) { acc1[i][j] = (v4f)(0.0f); acc2[i][j] = (v4f)(0.0f); }

  v8bf afr[4];
  v8bf b1fr[2][2], b2fr[2][2];

#define STG2_A(d, q, kt) __builtin_amdgcn_global_load_lds( \
    (__attribute__((address_space(1))) void*)(Ag + (size_t)(q) * (64 * K_DIM) + (size_t)(kt) * 64), \
    (__attribute__((address_space(3))) void*)(smem + (d) * 32768 + (q) * 8192 + wave * 1024), 16, 0, 0)
#define STG2_B1(d, q, kt) __builtin_amdgcn_global_load_lds( \
    (__attribute__((address_space(1))) void*)(Bg1 + (size_t)(q) * (64 * K_DIM) + (size_t)(kt) * 64), \
    (__attribute__((address_space(3))) void*)(smem + 65536 + (d) * 32768 + (q) * 8192 + wave * 1024), 16, 0, 0)
#define STG2_B2(d, q, kt) __builtin_amdgcn_global_load_lds( \
    (__attribute__((address_space(1))) void*)(Bg2 + (size_t)(q) * (64 * K_DIM) + (size_t)(kt) * 64), \
    (__attribute__((address_space(3))) void*)(smem + 65536 + (d) * 32768 + 16384 + (q) * 8192 + wave * 1024), 16, 0, 0)
#define LDA2(d, i, kk) (*(const v8bf*)(smem + (d) * 32768 + aRow + (i) * 2048 + (((kk) * 64 + qx) ^ cxor)))
#define LDB21(d, j, kk) (*(const v8bf*)(smem + 65536 + (d) * 32768 + bRow + (j) * 2048 + (((kk) * 64 + qx) ^ cxor)))
#define LDB22(d, j, kk) (*(const v8bf*)(smem + 65536 + (d) * 32768 + 16384 + bRow + (j) * 2048 + (((kk) * 64 + qx) ^ cxor)))
#define RD2_A(d, ih, kk) { _Pragma("unroll") for (int ii = 0; ii < 4; ++ii) afr[ii] = LDA2(d, (ih) * 4 + ii, kk); }
#define RD2_B(d, kk) { _Pragma("unroll") for (int j = 0; j < 2; ++j) { b1fr[j][kk] = LDB21(d, j, kk); b2fr[j][kk] = LDB22(d, j, kk); } }
#define MM2(ih, kk) \
  __builtin_amdgcn_s_barrier(); \
  asm volatile("s_waitcnt lgkmcnt(0)" ::: "memory"); \
  __builtin_amdgcn_s_setprio(1); \
  { _Pragma("unroll") for (int ii = 0; ii < 4; ++ii) { _Pragma("unroll") for (int j = 0; j < 2; ++j) { \
      acc1[(ih) * 4 + ii][j] = __builtin_amdgcn_mfma_f32_16x16x32_bf16(afr[ii], b1fr[j][(kk)], acc1[(ih) * 4 + ii][j], 0, 0, 0); \
      acc2[(ih) * 4 + ii][j] = __builtin_amdgcn_mfma_f32_16x16x32_bf16(afr[ii], b2fr[j][(kk)], acc2[(ih) * 4 + ii][j], 0, 0, 0); } } } \
  __builtin_amdgcn_s_setprio(0);
#define BAR() __builtin_amdgcn_s_barrier()
#define WAITV(n) asm volatile("s_waitcnt vmcnt(" #n ")" ::: "memory")

  // ---- Prologue: tile0 full (A q0-3, B1 q0-1, B2 q0-1), tile1 partial
  //      (A q0,q2, B1 q0,q1) — complement of main-loop ph1-2 staging. ----
  STG2_A(0, 0, 0); STG2_A(0, 1, 0); STG2_A(0, 2, 0); STG2_A(0, 3, 0);
  STG2_B1(0, 0, 0); STG2_B1(0, 1, 0); STG2_B2(0, 0, 0); STG2_B2(0, 1, 0);
  STG2_A(1, 0, 1); STG2_A(1, 2, 1); STG2_B1(1, 0, 1); STG2_B1(1, 1, 1);
  WAITV(4);
  BAR();

  for (int it = 0; it < 7; ++it) {
    const int t1 = 2 * it + 1, t2 = t1 + 1, t3 = t1 + 2;
    // ph1: buf0 (ih0,kk0)
    RD2_A(0, 0, 0); RD2_B(0, 0);
    STG2_B2(1, 0, t1); STG2_B2(1, 1, t1);
    MM2(0, 0); BAR();
    // ph2: buf0 (ih0,kk1)
    RD2_B(0, 1); RD2_A(0, 0, 1);
    STG2_A(1, 1, t1); STG2_A(1, 3, t1);
    MM2(0, 1); BAR();
    // ph3: buf0 (ih1,kk0)
    RD2_A(0, 1, 0);
    STG2_A(0, 0, t2); STG2_A(0, 2, t2);
    MM2(1, 0); BAR();
    // ph4: buf0 (ih1,kk1); counted wait for t1
    RD2_A(0, 1, 1);
    STG2_B1(0, 0, t2); STG2_B1(0, 1, t2);
    MM2(1, 1); WAITV(4); BAR();
    // ph5: buf1 (ih0,kk0)
    RD2_A(1, 0, 0); RD2_B(1, 0);
    STG2_B2(0, 0, t2); STG2_B2(0, 1, t2);
    MM2(0, 0); BAR();
    // ph6: buf1 (ih0,kk1)
    RD2_B(1, 1); RD2_A(1, 0, 1);
    STG2_A(0, 1, t2); STG2_A(0, 3, t2);
    MM2(0, 1); BAR();
    // ph7: buf1 (ih1,kk0)
    RD2_A(1, 1, 0);
    STG2_A(1, 0, t3); STG2_A(1, 2, t3);
    MM2(1, 0); BAR();
    // ph8: buf1 (ih1,kk1); counted wait for t2
    RD2_A(1, 1, 1);
    STG2_B1(1, 0, t3); STG2_B1(1, 1, t3);
    MM2(1, 1); WAITV(4); BAR();
  }
  // ---- Tail: tiles 14 (buf0), 15 (buf1) ----
  RD2_A(0, 0, 0); RD2_B(0, 0);
  STG2_B2(1, 0, 15); STG2_B2(1, 1, 15);
  MM2(0, 0); BAR();
  RD2_B(0, 1); RD2_A(0, 0, 1);
  STG2_A(1, 1, 15); STG2_A(1, 3, 15);
  MM2(0, 1); BAR();
  RD2_A(0, 1, 0); MM2(1, 0); BAR();
  RD2_A(0, 1, 1); MM2(1, 1); WAITV(0); BAR();
  RD2_A(1, 0, 0); RD2_B(1, 0); MM2(0, 0); BAR();
  RD2_B(1, 1); RD2_A(1, 0, 1); MM2(0, 1); BAR();
  RD2_A(1, 1, 0); MM2(1, 0); BAR();
  RD2_A(1, 1, 1); MM2(1, 1);

#undef STG2_A
#undef STG2_B1
#undef STG2_B2
#undef LDA2
#undef LDB21
#undef LDB22
#undef RD2_A
#undef RD2_B
#undef MM2
#undef BAR
#undef WAITV

  // ---- Fused final epilogue: out = (max(pmax,L)+c2)*max(pmax,L)+c1.
  // Compact store burst at block exit (R2 lesson).  fp32 stores: 16
  // consecutive r16 lanes = 64B contiguous per (i,j,r). ----
  const int bidx = mtile0 >> 12;
  const int sub0 = (mtile0 & 4095) >> 5;
#pragma unroll
  for (int i = 0; i < 8; ++i) {
    const int subr = sub0 + wr * 4 + (i >> 1);
#pragma unroll
    for (int j = 0; j < 2; ++j) {
      const int col = ncol0 + wc * 32 + j * 16 + r16;
      const float pm = pmax[((size_t)bidx * NSUB + subr) * HIDDEN + col];
      const int row0 = mtile0 + wr * 128 + i * 16 + quad * 4;
#pragma unroll
      for (int r = 0; r < 4; ++r) {
        size_t idx = (size_t)(row0 + r) * HIDDEN + col;
        float m = fmaxf(pm, bf16_to_f32(Lp[idx]));
        out[idx] = (m + acc2[i][j][r]) * m + acc1[i][j][r];
      }
    }
  }
}

extern "C" void kernel_launch(void* const* d_in, const int* in_sizes, int n_in,
                              void* d_out, int out_size, void* d_ws, size_t ws_size,
                              hipStream_t stream) {
  const float* X = (const float*)d_in[0];
  const float* W0 = (const float*)d_in[1];
  const float* W1 = (const float*)d_in[2];
  const float* W2 = (const float*)d_in[3];
  float* out = (float*)d_out;

  // Workspace: Xb, Wb, Lp, cmax, pmax (C1/C2 regions no longer used)
  char* ws = (char*)d_ws;
  unsigned short* Xb = (unsigned short*)ws;
  unsigned short* Wb = (unsigned short*)(ws + 33554432);
  unsigned short* Lp = (unsigned short*)(ws + 33554432 + 6291456);
  float* cmax = (float*)(ws + 4 * 33554432 + 6291456);
  float* pmax = (float*)(ws + 4 * 33554432 + 6291456 + 2097152);

  convert_kernel<<<19456, 256, 0, stream>>>(X, W0, W1, W2, Xb, Wb);

  // S-GEMM + cummax: 4 n-tiles x 64 m-tiles = 256 blocks (1/CU, 1 round)
  gemm_s_kernel<<<256, 512, 131072, stream>>>((const bf16_t*)Xb, (const bf16_t*)Wb,
                                              Lp, cmax);

  dim3 pgrid(4, BATCH);
  prefix_kernel<<<pgrid, 256, 0, stream>>>(cmax, pmax);

  // Dual GEMM (C1,C2) + fused final: 8 n-tiles x 64 m-tiles = 512 blocks
  gemm_f_kernel<<<512, 512, 131072, stream>>>((const bf16_t*)Xb, (const bf16_t*)Wb,
                                              Lp, pmax, out);
}